// Round 10
// baseline (373.403 us; speedup 1.0000x reference)
//
#include <hip/hip_runtime.h>
#include <hip/hip_fp16.h>

#define BN_EPS 1e-5f
#define EPB 8192                 // edges per block in bin passes (2x: fewer partial lines)
#define PADCAP 4608              // per-bin capacity (mean 4096 + 8 sigma)
#define FP8_SCALE 16.0f          // table pre-scale: e4m3 sweet band, no denormals
#define FP8_INV (1.0f / 16.0f)
#define W15_INV (1.0f / 32768.0f)
#define NPOOL 8                  // pooled replicas (contention spread)

typedef __attribute__((ext_vector_type(2))) float vfloat2;
typedef __attribute__((ext_vector_type(8))) short short8;   // 8 x bf16 frag
typedef __attribute__((ext_vector_type(4))) float f32x4;

__device__ __forceinline__ float fatomic_add(float* p, float v) {
    return unsafeAtomicAdd(p, v);  // HW global_atomic_add_f32
}

__device__ __forceinline__ unsigned short f2bf(float f) {   // f32 -> bf16 (RNE-ish)
    unsigned int u = __float_as_uint(f);
    return (unsigned short)((u + 0x7FFFu + ((u >> 16) & 1u)) >> 16);
}

// m204 bijective XCD-chunked swizzle: consecutive logical blocks -> same XCD
__device__ __forceinline__ int xcd_swz(int bid, int nwg) {
    int xcd = bid & 7, k = bid >> 3;
    int q = nwg >> 3, r = nwg & 7;
    return (xcd < r ? xcd * (q + 1) : r * (q + 1) + (xcd - r) * q) + k;
}

// ---------- B1: scatter packed edge records into padded bin staging ----------
// staged rec (8B, NT-stored): lo = src | (c_local << 24), hi = w15
// block 0 zeroes pooled8; block 1 builds the bf16 W^T tables
__global__ __launch_bounds__(256) void k_binscatter(const int* __restrict__ rowi,
                                                    const int* __restrict__ coli,
                                                    const float* __restrict__ ew,
                                                    unsigned int* __restrict__ binCursor,
                                                    long long* __restrict__ staged,
                                                    float* __restrict__ pooled8,
                                                    const float* __restrict__ W1,
                                                    const float* __restrict__ W2,
                                                    const float* __restrict__ W3,
                                                    short* __restrict__ WT,
                                                    int E, int NB, int PZ) {
    __shared__ unsigned int h[512];
    __shared__ unsigned int bb[512];
    int tid = threadIdx.x;
    if (blockIdx.x == 0) {
        for (int i = tid; i < PZ; i += 256) pooled8[i] = 0.f;
    } else if (blockIdx.x == 1) {              // fold W pre-transpose here
        const float* Wm[3] = {W1, W2, W3};
#pragma unroll
        for (int m = 0; m < 3; ++m) {
            const float* W = Wm[m];
            short* o = WT + m * 4096;
            for (int i = tid; i < 4096; i += 256)
                o[i] = (short)f2bf(W[(i & 63) * 64 + (i >> 6)]);
        }
    }
    for (int i = tid; i < 512; i += 256) h[i] = 0;
    __syncthreads();
    int base = blockIdx.x * EPB;
    int lim = min(EPB, E - base);
    unsigned short rank[32];
    int nj = (lim - tid + 255) / 256;           // iterations this thread runs
    for (int j = 0; j < nj; ++j) {
        int e = base + tid + j * 256;
        rank[j] = (unsigned short)atomicAdd(&h[(unsigned)coli[e] >> 8], 1u);
    }
    __syncthreads();
    for (int b = tid; b < NB; b += 256)
        bb[b] = h[b] ? atomicAdd(&binCursor[b], h[b]) : 0u;
    __syncthreads();
    for (int j = 0; j < nj; ++j) {
        int e = base + tid + j * 256;
        unsigned int c = (unsigned)coli[e];
        unsigned int b = c >> 8;
        unsigned int lo = (unsigned)rowi[e] | ((c & 255u) << 24);
        unsigned int w15 = min((unsigned int)(ew[e] * 32768.f + 0.5f), 32767u);
        long long rec = ((long long)w15 << 32) | (long long)lo;
        __builtin_nontemporal_store(rec, &staged[(size_t)b * PADCAP + bb[b] + rank[j]]);
    }
}

// ---------- B2: per-bin LDS counting sort -> csr(4B recs), se, dinv ----------
// csr record: (w15 << 17) | src
__global__ __launch_bounds__(256) void k_binfinal(const long long* __restrict__ staged,
                                                  const unsigned int* __restrict__ binCursor,
                                                  unsigned int* __restrict__ csr,
                                                  int2* __restrict__ se,
                                                  float* __restrict__ dinv,
                                                  int N) {
    __shared__ int2 recs[PADCAP];
    __shared__ unsigned int cnt[256];
    __shared__ unsigned int deg[256];   // integer sum of w15
    __shared__ int sc[256];
    __shared__ unsigned int cur[256];
    int tid = threadIdx.x;
    int b = blockIdx.x;
    int s0 = b * PADCAP;
    int n = (int)binCursor[b];          // actual bin count
    cnt[tid] = 0;
    deg[tid] = 0;
    __syncthreads();
    for (int i = tid; i < n; i += 256) {
        long long r = __builtin_nontemporal_load(&staged[s0 + i]);
        int2 rec;
        rec.x = (int)(unsigned int)r;
        rec.y = (int)(unsigned int)(r >> 32);
        recs[i] = rec;
        unsigned int cl = (unsigned)rec.x >> 24;
        atomicAdd(&cnt[cl], 1u);
        atomicAdd(&deg[cl], (unsigned int)rec.y);
    }
    __syncthreads();
    int v = (int)cnt[tid];
    sc[tid] = v;
    __syncthreads();
    for (int off = 1; off < 256; off <<= 1) {
        int add = (tid >= off) ? sc[tid - off] : 0;
        __syncthreads();
        sc[tid] += add;
        __syncthreads();
    }
    int lpre = sc[tid] - v;             // exclusive prefix within bin
    cur[tid] = (unsigned int)lpre;
    int c = b * 256 + tid;
    if (c < N) {
        se[c] = make_int2(s0 + lpre, s0 + lpre + v);
        dinv[c] = rsqrtf(1.0f + (float)deg[tid] * W15_INV);
    }
    __syncthreads();
    for (int i = tid; i < n; i += 256) {   // direct scatter, NT (write-once)
        int2 rec = recs[i];
        unsigned int cl = (unsigned)rec.x >> 24;
        unsigned int p = atomicAdd(&cur[cl], 1u);
        __builtin_nontemporal_store(
            ((unsigned int)rec.y << 17) | ((unsigned)rec.x & 0x1FFFFu),
            &csr[s0 + p]);
    }
}

// ------- GEMM (MFMA bf16): t8 = fp8( 16 * dinv .* (x @ W) ), 16 rows/block -------
__global__ __launch_bounds__(256) void k_gemm(const float* __restrict__ x,
                                              const short* __restrict__ WTg,
                                              const float* __restrict__ dinv,
                                              int* __restrict__ th4, int n) {
    __shared__ short Wt[64][72];     // W^T bf16, +8 pad
    __shared__ short xs[16][72];     // x tile bf16
    __shared__ float outs[16][68];   // f32 result bounce for repack
    int tid = threadIdx.x;
    {   // conflict-free staging: lanes write consecutive shorts of a row
        const int* WTi = (const int*)WTg;      // 2048 ints
        for (int i = tid; i < 2048; i += 256)
            *(int*)&Wt[i >> 5][(i & 31) * 2] = WTi[i];
    }
    int row0 = blockIdx.x * 16;
    int nrows = min(16, n - row0);
    {                                             // stage x rows -> bf16
        int r = tid >> 4, c4 = (tid & 15) * 4;
        float4 v = make_float4(0.f, 0.f, 0.f, 0.f);
        if (r < nrows)
            v = ((const float4*)(x + (size_t)(row0 + r) * 64))[tid & 15];
        xs[r][c4 + 0] = (short)f2bf(v.x);
        xs[r][c4 + 1] = (short)f2bf(v.y);
        xs[r][c4 + 2] = (short)f2bf(v.z);
        xs[r][c4 + 3] = (short)f2bf(v.w);
    }
    __syncthreads();
    int wv = tid >> 6, lane = tid & 63;
    int mn = lane & 15, kg = (lane >> 4) * 8;
    f32x4 acc = {0.f, 0.f, 0.f, 0.f};
    short8 a0 = *(const short8*)&xs[mn][kg];
    short8 a1 = *(const short8*)&xs[mn][kg + 32];
    short8 b0 = *(const short8*)&Wt[wv * 16 + mn][kg];
    short8 b1 = *(const short8*)&Wt[wv * 16 + mn][kg + 32];
    acc = __builtin_amdgcn_mfma_f32_16x16x32_bf16(a0, b0, acc, 0, 0, 0);
    acc = __builtin_amdgcn_mfma_f32_16x16x32_bf16(a1, b1, acc, 0, 0, 0);
#pragma unroll
    for (int r = 0; r < 4; ++r)
        outs[(lane >> 4) * 4 + r][wv * 16 + mn] = acc[r];
    __syncthreads();
    int rl = tid >> 4, fq = tid & 15;
    if (rl < nrows) {
        float d = dinv[row0 + rl] * FP8_SCALE;
        float4 o = *(const float4*)&outs[rl][fq * 4];
        int p = __builtin_amdgcn_cvt_pk_fp8_f32(o.x * d, o.y * d, 0, false);
        p = __builtin_amdgcn_cvt_pk_fp8_f32(o.z * d, o.w * d, p, true);
        th4[(row0 + rl) * 16 + fq] = p;
    }
}

// ------- FUSED: gather(th4_in) + ReLU + BN + next-layer GEMM -> th4_out -------
__global__ __launch_bounds__(256) void k_fusedgg(const unsigned int* __restrict__ csr,
                                                 const int2* __restrict__ se,
                                                 const int* __restrict__ th4_in,
                                                 const float* __restrict__ dinv,
                                                 const float* __restrict__ bias,
                                                 const float* __restrict__ gam,
                                                 const float* __restrict__ bet,
                                                 const float* __restrict__ mu,
                                                 const float* __restrict__ var,
                                                 const short* __restrict__ WTg,
                                                 int* __restrict__ th4_out, int n) {
    __shared__ short Wt[64][72];     // next-layer W^T bf16
    __shared__ short xs[16][72];     // h tile bf16 (gather output)
    __shared__ float outs[16][68];   // f32 gemm result bounce
    int tid = threadIdx.x;
    {   // conflict-free staging of pre-transposed W
        const int* WTi = (const int*)WTg;
        for (int i = tid; i < 2048; i += 256)
            *(int*)&Wt[i >> 5][(i & 31) * 2] = WTi[i];
    }
    int nb = xcd_swz(blockIdx.x, gridDim.x);
    int w = tid >> 6;
    int lane = tid & 63;
    int q = lane >> 4;           // quarter -> node owner
    int l = lane & 15;           // feature quad index
    int node = nb * 16 + w * 4 + q;
    bool valid = node < n;
    float4 b4 = ((const float4*)bias)[l];
    float4 m4 = ((const float4*)mu)[l];
    float4 v4 = ((const float4*)var)[l];
    float4 G4 = ((const float4*)gam)[l];
    float4 B4 = ((const float4*)bet)[l];
    float4 scf, shf;
    scf.x = rsqrtf(v4.x + BN_EPS) * G4.x;  shf.x = B4.x - m4.x * scf.x;
    scf.y = rsqrtf(v4.y + BN_EPS) * G4.y;  shf.y = B4.y - m4.y * scf.y;
    scf.z = rsqrtf(v4.z + BN_EPS) * G4.z;  shf.z = B4.z - m4.z * scf.z;
    scf.w = rsqrtf(v4.w + BN_EPS) * G4.w;  shf.w = B4.w - m4.w * scf.w;

    float4 av[4];
    av[0] = make_float4(0.f, 0.f, 0.f, 0.f);
    av[1] = av[0]; av[2] = av[0]; av[3] = av[0];
    float4 sf = av[0];                       // self-loop (weight 1, unscaled)
    int e = 0, eend = 0;
    float dv = 0.f;
    if (valid) {
        int2 ext = se[node];
        e = ext.x; eend = ext.y;
        dv = dinv[node];
        int sv = th4_in[node * 16 + l];
        vfloat2 lo = __builtin_amdgcn_cvt_pk_f32_fp8(sv, false);
        vfloat2 hi = __builtin_amdgcn_cvt_pk_f32_fp8(sv, true);
        sf = make_float4(lo.x, lo.y, hi.x, hi.y);
    }
    while (__any(e < eend)) {
        if (e < eend) {                      // exec-masked: done quarters idle
            unsigned int cc[8];
            int rr[8];
#pragma unroll
            for (int j = 0; j < 8; ++j)      // unclamped: csr has 64B slack,
                cc[j] = __builtin_nontemporal_load(&csr[e + j]);   // wj guards
#pragma unroll
            for (int j = 0; j < 8; ++j)
                rr[j] = th4_in[(int)((cc[j] & 0x1FFFFu) << 4) + l];
#pragma unroll
            for (int j = 0; j < 8; ++j) {
                float wj = (e + j < eend) ? (float)(cc[j] >> 17) : 0.f;
                vfloat2 lo = __builtin_amdgcn_cvt_pk_f32_fp8(rr[j], false);
                vfloat2 hi = __builtin_amdgcn_cvt_pk_f32_fp8(rr[j], true);
                av[j & 3].x = fmaf(wj, lo.x, av[j & 3].x);
                av[j & 3].y = fmaf(wj, lo.y, av[j & 3].y);
                av[j & 3].z = fmaf(wj, hi.x, av[j & 3].z);
                av[j & 3].w = fmaf(wj, hi.y, av[j & 3].w);
            }
        }
        e += 8;
    }
    float4 res = make_float4(0.f, 0.f, 0.f, 0.f);
    if (valid) {
        float4 acc;
        acc.x = ((av[0].x + av[1].x) + (av[2].x + av[3].x)) * W15_INV + sf.x;
        acc.y = ((av[0].y + av[1].y) + (av[2].y + av[3].y)) * W15_INV + sf.y;
        acc.z = ((av[0].z + av[1].z) + (av[2].z + av[3].z)) * W15_INV + sf.z;
        acc.w = ((av[0].w + av[1].w) + (av[2].w + av[3].w)) * W15_INV + sf.w;
        float d = dv * FP8_INV;              // undo table pre-scale
        float r0 = fmaxf(d * acc.x + b4.x, 0.f);   // ReLU then BN
        float r1 = fmaxf(d * acc.y + b4.y, 0.f);
        float r2 = fmaxf(d * acc.z + b4.z, 0.f);
        float r3 = fmaxf(d * acc.w + b4.w, 0.f);
        res.x = r0 * scf.x + shf.x;
        res.y = r1 * scf.y + shf.y;
        res.z = r2 * scf.z + shf.z;
        res.w = r3 * scf.w + shf.w;
    }
    {   // h row -> LDS bf16 (zeros for invalid nodes)
        int nl = w * 4 + q;
        union { unsigned short s[4]; int2 i2; } u;
        u.s[0] = f2bf(res.x); u.s[1] = f2bf(res.y);
        u.s[2] = f2bf(res.z); u.s[3] = f2bf(res.w);
        *(int2*)&xs[nl][4 * l] = u.i2;
    }
    __syncthreads();
    // ------- MFMA gemm on the 16-row h tile -------
    int mn = lane & 15, kg = (lane >> 4) * 8;
    f32x4 acc = {0.f, 0.f, 0.f, 0.f};
    short8 a0 = *(const short8*)&xs[mn][kg];
    short8 a1 = *(const short8*)&xs[mn][kg + 32];
    short8 b0 = *(const short8*)&Wt[w * 16 + mn][kg];
    short8 b1 = *(const short8*)&Wt[w * 16 + mn][kg + 32];
    acc = __builtin_amdgcn_mfma_f32_16x16x32_bf16(a0, b0, acc, 0, 0, 0);
    acc = __builtin_amdgcn_mfma_f32_16x16x32_bf16(a1, b1, acc, 0, 0, 0);
#pragma unroll
    for (int r = 0; r < 4; ++r)
        outs[(lane >> 4) * 4 + r][w * 16 + mn] = acc[r];
    __syncthreads();
    int rl = tid >> 4, fq = tid & 15;
    int row = nb * 16 + rl;
    if (row < n) {
        float d = dinv[row] * FP8_SCALE;
        float4 o = *(const float4*)&outs[rl][fq * 4];
        int p = __builtin_amdgcn_cvt_pk_fp8_f32(o.x * d, o.y * d, 0, false);
        p = __builtin_amdgcn_cvt_pk_fp8_f32(o.z * d, o.w * d, p, true);
        th4_out[row * 16 + fq] = p;
    }
}

// ------- final gather + BN + pool: block-level LDS merge, 8-way spread -------
__global__ __launch_bounds__(256) void k_gather(const unsigned int* __restrict__ csr,
                                                const int2* __restrict__ se,
                                                const int* __restrict__ th4,
                                                const float* __restrict__ dinv,
                                                const float* __restrict__ bias,
                                                const float* __restrict__ gam,
                                                const float* __restrict__ bet,
                                                const float* __restrict__ mu,
                                                const float* __restrict__ var,
                                                const int* __restrict__ batch,
                                                float* __restrict__ pooled8,
                                                int n, int G64) {
    __shared__ float vals[4][64];
    __shared__ int wbid[4];
    int nb = xcd_swz(blockIdx.x, gridDim.x);
    int w = threadIdx.x >> 6;
    int lane = threadIdx.x & 63;
    int q = lane >> 4;           // quarter -> node owner
    int l = lane & 15;           // feature quad index
    int node = nb * 16 + w * 4 + q;
    bool valid = node < n;
    float* myPool = pooled8 + (size_t)(blockIdx.x & (NPOOL - 1)) * G64;
    float4 b4 = ((const float4*)bias)[l];
    float4 m4 = ((const float4*)mu)[l];
    float4 v4 = ((const float4*)var)[l];
    float4 G4 = ((const float4*)gam)[l];
    float4 B4 = ((const float4*)bet)[l];
    float4 scf, shf;
    scf.x = rsqrtf(v4.x + BN_EPS) * G4.x;  shf.x = B4.x - m4.x * scf.x;
    scf.y = rsqrtf(v4.y + BN_EPS) * G4.y;  shf.y = B4.y - m4.y * scf.y;
    scf.z = rsqrtf(v4.z + BN_EPS) * G4.z;  shf.z = B4.z - m4.z * scf.z;
    scf.w = rsqrtf(v4.w + BN_EPS) * G4.w;  shf.w = B4.w - m4.w * scf.w;

    float4 av[4];
    av[0] = make_float4(0.f, 0.f, 0.f, 0.f);
    av[1] = av[0]; av[2] = av[0]; av[3] = av[0];
    float4 sf = av[0];
    int e = 0, eend = 0;
    float dv = 0.f;
    if (valid) {
        int2 ext = se[node];
        e = ext.x; eend = ext.y;
        dv = dinv[node];
        int sv = th4[node * 16 + l];
        vfloat2 lo = __builtin_amdgcn_cvt_pk_f32_fp8(sv, false);
        vfloat2 hi = __builtin_amdgcn_cvt_pk_f32_fp8(sv, true);
        sf = make_float4(lo.x, lo.y, hi.x, hi.y);
    }
    while (__any(e < eend)) {
        if (e < eend) {
            unsigned int cc[8];
            int rr[8];
#pragma unroll
            for (int j = 0; j < 8; ++j)
                cc[j] = __builtin_nontemporal_load(&csr[e + j]);
#pragma unroll
            for (int j = 0; j < 8; ++j)
                rr[j] = th4[(int)((cc[j] & 0x1FFFFu) << 4) + l];
#pragma unroll
            for (int j = 0; j < 8; ++j) {
                float wj = (e + j < eend) ? (float)(cc[j] >> 17) : 0.f;
                vfloat2 lo = __builtin_amdgcn_cvt_pk_f32_fp8(rr[j], false);
                vfloat2 hi = __builtin_amdgcn_cvt_pk_f32_fp8(rr[j], true);
                av[j & 3].x = fmaf(wj, lo.x, av[j & 3].x);
                av[j & 3].y = fmaf(wj, lo.y, av[j & 3].y);
                av[j & 3].z = fmaf(wj, hi.x, av[j & 3].z);
                av[j & 3].w = fmaf(wj, hi.y, av[j & 3].w);
            }
        }
        e += 8;
    }
    float4 res = make_float4(0.f, 0.f, 0.f, 0.f);
    if (valid) {
        float4 acc;
        acc.x = ((av[0].x + av[1].x) + (av[2].x + av[3].x)) * W15_INV + sf.x;
        acc.y = ((av[0].y + av[1].y) + (av[2].y + av[3].y)) * W15_INV + sf.y;
        acc.z = ((av[0].z + av[1].z) + (av[2].z + av[3].z)) * W15_INV + sf.z;
        acc.w = ((av[0].w + av[1].w) + (av[2].w + av[3].w)) * W15_INV + sf.w;
        float d = dv * FP8_INV;
        float r0 = d * acc.x + b4.x;         // no ReLU before bn3
        float r1 = d * acc.y + b4.y;
        float r2 = d * acc.z + b4.z;
        float r3 = d * acc.w + b4.w;
        res.x = r0 * scf.x + shf.x;
        res.y = r1 * scf.y + shf.y;
        res.z = r2 * scf.z + shf.z;
        res.w = r3 * scf.w + shf.w;
    }
    int bid = valid ? batch[node] : -1;
    int bid0 = __shfl(bid, 0);
    bool same = __all(bid == bid0);
    if (same) {                              // common: wave's 4 nodes one graph
        res.x += __shfl_xor(res.x, 16);
        res.y += __shfl_xor(res.y, 16);
        res.z += __shfl_xor(res.z, 16);
        res.w += __shfl_xor(res.w, 16);
        res.x += __shfl_xor(res.x, 32);
        res.y += __shfl_xor(res.y, 32);
        res.z += __shfl_xor(res.z, 32);
        res.w += __shfl_xor(res.w, 32);
        if (q == 0) ((float4*)&vals[w][0])[l] = res;
        if (lane == 0) wbid[w] = bid0;       // may be -1 if wave invalid
    } else {
        if (valid) {                         // rare boundary wave: direct flush
            float* pp = myPool + bid * 64 + 4 * l;
            fatomic_add(pp + 0, res.x);
            fatomic_add(pp + 1, res.y);
            fatomic_add(pp + 2, res.z);
            fatomic_add(pp + 3, res.w);
        }
        if (lane == 0) wbid[w] = -1;         // nothing in LDS for this wave
    }
    __syncthreads();
    if (w == 0) {                            // wave 0: merge 4 wave-partials
        int f = threadIdx.x;                 // 0..63
        float s2 = 0.f;
        int cur = -1;
#pragma unroll
        for (int i = 0; i < 4; ++i) {
            int bi = wbid[i];
            if (bi < 0) continue;
            if (bi == cur) {
                s2 += vals[i][f];
            } else {
                if (cur >= 0) fatomic_add(&myPool[cur * 64 + f], s2);
                cur = bi;
                s2 = vals[i][f];
            }
        }
        if (cur >= 0) fatomic_add(&myPool[cur * 64 + f], s2);
    }
}

// ---- final: out[g] = ReLU(sum_8 pooled8[g]) @ Wfc + bfc (block per graph) ----
__global__ __launch_bounds__(64) void k_fc(const float* __restrict__ pooled8,
                                           const float* __restrict__ Wfc,
                                           const float* __restrict__ bfc,
                                           float* __restrict__ out, int G) {
    int g = blockIdx.x;
    int f = threadIdx.x;         // 0..63
    int G64 = G * 64;
    float p = 0.f;
#pragma unroll
    for (int c = 0; c < NPOOL; ++c) p += pooled8[c * G64 + g * 64 + f];
    float s = fmaxf(p, 0.f) * Wfc[f];
#pragma unroll
    for (int off = 1; off < 64; off <<= 1) s += __shfl_xor(s, off);
    if (f == 0) out[g] = s + bfc[0];
}

extern "C" void kernel_launch(void* const* d_in, const int* in_sizes, int n_in,
                              void* d_out, int out_size, void* d_ws, size_t ws_size,
                              hipStream_t stream) {
    const float* x    = (const float*)d_in[0];
    const int*   eidx = (const int*)d_in[1];
    const float* ew   = (const float*)d_in[2];
    const int*   batch= (const int*)d_in[3];
    const float* W1 = (const float*)d_in[4];
    const float* b1 = (const float*)d_in[5];
    const float* W2 = (const float*)d_in[6];
    const float* b2 = (const float*)d_in[7];
    const float* W3 = (const float*)d_in[8];
    const float* b3 = (const float*)d_in[9];
    const float* Wfc = (const float*)d_in[10];
    const float* bfc = (const float*)d_in[11];
    const float* g1 = (const float*)d_in[12];
    const float* be1 = (const float*)d_in[13];
    const float* m1 = (const float*)d_in[14];
    const float* v1 = (const float*)d_in[15];
    const float* g2 = (const float*)d_in[16];
    const float* be2 = (const float*)d_in[17];
    const float* m2 = (const float*)d_in[18];
    const float* v2 = (const float*)d_in[19];
    const float* g3 = (const float*)d_in[20];
    const float* be3 = (const float*)d_in[21];
    const float* m3 = (const float*)d_in[22];
    const float* v3 = (const float*)d_in[23];

    const int N = in_sizes[0] / 64;     // 100000
    const int E = in_sizes[1] / 2;      // 1600000
    const int G = out_size;             // 128
    const int* rowi = eidx;
    const int* coli = eidx + E;
    const int NB = (N + 255) >> 8;      // 391 destination bins

    // -------- workspace layout (256B aligned) --------
    char* ws = (char*)d_ws;
    size_t off = 0;
    auto alloc = [&](size_t bytes) {
        char* p = ws + off;
        off += (bytes + 255) & ~(size_t)255;
        return p;
    };
    unsigned int* binCursor = (unsigned int*)alloc(512 * 4);
    float* dinv   = (float*)alloc((size_t)N * 4);
    int2*  se     = (int2*) alloc((size_t)N * 8);
    unsigned int* csr = (unsigned int*)alloc((size_t)NB * PADCAP * 4 + 256);
    int*   th4a   = (int*)  alloc((size_t)N * 64);        // fp8 table ping
    int*   th4b   = (int*)  alloc((size_t)N * 64);        // fp8 table pong
    float* pooled8 = (float*)alloc((size_t)NPOOL * G * 64 * 4);
    short* wtg    = (short*)alloc(3 * 4096 * 2);          // W1T/W2T/W3T bf16
    long long* staged = (long long*)alloc((size_t)NB * PADCAP * 8);

    const int bblk = (E + EPB - 1) / EPB;   // 196
    const int gblk = (N + 15) / 16;         // 6250: 16 nodes/block (4/wave)
    const int mblk = (N + 15) / 16;

    // -------- binned CSR build + normalization + W^T (2 kernels) --------
    hipMemsetAsync(binCursor, 0, 512 * 4, stream);
    k_binscatter<<<bblk, 256, 0, stream>>>(rowi, coli, ew, binCursor, staged,
                                           pooled8, W1, W2, W3, wtg,
                                           E, NB, NPOOL * G * 64);
    k_binfinal<<<NB, 256, 0, stream>>>(staged, binCursor, csr, se, dinv, N);

    // -------- layer 1 gemm --------
    k_gemm<<<mblk, 256, 0, stream>>>(x, wtg, dinv, th4a, N);
    // -------- gather1 + BN1 + gemm2 (fused) --------
    k_fusedgg<<<gblk, 256, 0, stream>>>(csr, se, th4a, dinv, b1, g1, be1, m1, v1,
                                        wtg + 4096, th4b, N);
    // -------- gather2 + BN2 + gemm3 (fused) --------
    k_fusedgg<<<gblk, 256, 0, stream>>>(csr, se, th4b, dinv, b2, g2, be2, m2, v2,
                                        wtg + 8192, th4a, N);
    // -------- gather3 + BN3 + pool (block-merged atomics) --------
    k_gather<<<gblk, 256, 0, stream>>>(csr, se, th4a, dinv, b3, g3, be3, m3, v3,
                                       batch, pooled8, N, G * 64);
    // -------- FC head --------
    k_fc<<<G, 64, 0, stream>>>(pooled8, Wfc, bfc, (float*)d_out, G);
}

// Round 11
// 296.267 us; speedup vs baseline: 1.2604x; 1.2604x over previous
//
#include <hip/hip_runtime.h>
#include <hip/hip_fp16.h>

#define BN_EPS 1e-5f
#define EPB 4096                 // edges per block in bin passes
#define PADCAP 4608              // per-bin capacity (mean 4096 + 8 sigma)
#define FP8_SCALE 16.0f          // table pre-scale: e4m3 sweet band, no denormals
#define FP8_INV (1.0f / 16.0f)
#define W15_INV (1.0f / 32768.0f)
#define NPOOL 8                  // pooled replicas (contention spread)

typedef __attribute__((ext_vector_type(2))) float vfloat2;
typedef __attribute__((ext_vector_type(8))) short short8;   // 8 x bf16 frag
typedef __attribute__((ext_vector_type(4))) float f32x4;

__device__ __forceinline__ float fatomic_add(float* p, float v) {
    return unsafeAtomicAdd(p, v);  // HW global_atomic_add_f32
}

__device__ __forceinline__ unsigned short f2bf(float f) {   // f32 -> bf16 (RNE-ish)
    unsigned int u = __float_as_uint(f);
    return (unsigned short)((u + 0x7FFFu + ((u >> 16) & 1u)) >> 16);
}

// m204 bijective XCD-chunked swizzle: consecutive logical blocks -> same XCD
__device__ __forceinline__ int xcd_swz(int bid, int nwg) {
    int xcd = bid & 7, k = bid >> 3;
    int q = nwg >> 3, r = nwg & 7;
    return (xcd < r ? xcd * (q + 1) : r * (q + 1) + (xcd - r) * q) + k;
}

// ---------- B1: bin-sorted scatter into padded bin staging ----------
// Records are counting-sorted by bin in LDS first, so the global dump writes
// contiguous ~84B runs per bin (L2 write-coalescing friendly), instead of 64
// scattered partial-line touches per wave-instruction.
// staged rec: x = src | (c_local << 24), y = w15 | (bin << 15)
// block 0 zeroes pooled8; block 1 builds the bf16 W^T tables
__global__ __launch_bounds__(256) void k_binscatter(const int* __restrict__ rowi,
                                                    const int* __restrict__ coli,
                                                    const float* __restrict__ ew,
                                                    unsigned int* __restrict__ binCursor,
                                                    int2* __restrict__ staged,
                                                    float* __restrict__ pooled8,
                                                    const float* __restrict__ W1,
                                                    const float* __restrict__ W2,
                                                    const float* __restrict__ W3,
                                                    short* __restrict__ WT,
                                                    int E, int NB, int PZ) {
    __shared__ unsigned int h[512];      // per-bin counts
    __shared__ unsigned int lo[512];     // exclusive prefix (local offsets)
    __shared__ unsigned int dd[512];     // global dump delta per bin
    __shared__ unsigned int ps[256];     // pair-sum scan buffer
    __shared__ int2 lsorted[EPB];        // 32KB bin-sorted records
    int tid = threadIdx.x;
    if (blockIdx.x == 0) {
        for (int i = tid; i < PZ; i += 256) pooled8[i] = 0.f;
    } else if (blockIdx.x == 1) {              // fold W pre-transpose here
        const float* Wm[3] = {W1, W2, W3};
#pragma unroll
        for (int m = 0; m < 3; ++m) {
            const float* W = Wm[m];
            short* o = WT + m * 4096;
            for (int i = tid; i < 4096; i += 256)
                o[i] = (short)f2bf(W[(i & 63) * 64 + (i >> 6)]);
        }
    }
    for (int i = tid; i < 512; i += 256) h[i] = 0;
    __syncthreads();
    int base = blockIdx.x * EPB;
    int lim = min(EPB, E - base);
    unsigned short rank[16];
    int nj = (lim - tid + 255) / 256;           // iterations this thread runs
    for (int j = 0; j < nj; ++j) {
        int e = base + tid + j * 256;
        rank[j] = (unsigned short)atomicAdd(&h[(unsigned)coli[e] >> 8], 1u);
    }
    __syncthreads();
    // exclusive prefix over 512 bins (pair + 256-scan + fixup)
    unsigned int a0 = h[2 * tid], a1 = h[2 * tid + 1];
    ps[tid] = a0 + a1;
    __syncthreads();
    for (int off = 1; off < 256; off <<= 1) {
        unsigned int add = (tid >= off) ? ps[tid - off] : 0u;
        __syncthreads();
        ps[tid] += add;
        __syncthreads();
    }
    unsigned int excl = ps[tid] - (a0 + a1);
    lo[2 * tid] = excl;
    lo[2 * tid + 1] = excl + a0;
    __syncthreads();
    for (int b = tid; b < NB; b += 256) {       // reserve global + dump delta
        unsigned int bbv = h[b] ? atomicAdd(&binCursor[b], h[b]) : 0u;
        dd[b] = (unsigned int)(b * PADCAP) + bbv - lo[b];
    }
    __syncthreads();
    for (int j = 0; j < nj; ++j) {              // scatter into sorted LDS
        int e = base + tid + j * 256;
        unsigned int c = (unsigned)coli[e];
        unsigned int b = c >> 8;
        int2 rec;
        rec.x = rowi[e] | (int)((c & 255u) << 24);
        unsigned int w15 = min((unsigned int)(ew[e] * 32768.f + 0.5f), 32767u);
        rec.y = (int)(w15 | (b << 15));
        lsorted[lo[b] + rank[j]] = rec;
    }
    __syncthreads();
    for (int i = tid; i < lim; i += 256) {      // contiguous per-bin runs out
        int2 rec = lsorted[i];
        unsigned int b = ((unsigned)rec.y >> 15) & 0x1FFu;
        staged[dd[b] + i] = rec;
    }
}

// ---------- B2: per-bin LDS counting sort -> csr(4B recs), se, dinv ----------
// csr record: (w15 << 17) | src   (staged rec.y carries bin bits: mask 0x7FFF)
__global__ __launch_bounds__(256) void k_binfinal(const int2* __restrict__ staged,
                                                  const unsigned int* __restrict__ binCursor,
                                                  unsigned int* __restrict__ csr,
                                                  int2* __restrict__ se,
                                                  float* __restrict__ dinv,
                                                  int N) {
    __shared__ int2 recs[PADCAP];
    __shared__ unsigned int cnt[256];
    __shared__ unsigned int deg[256];   // integer sum of w15
    __shared__ int sc[256];
    __shared__ unsigned int cur[256];
    int tid = threadIdx.x;
    int b = blockIdx.x;
    int s0 = b * PADCAP;
    int n = (int)binCursor[b];          // actual bin count
    cnt[tid] = 0;
    deg[tid] = 0;
    __syncthreads();
    for (int i = tid; i < n; i += 256) {
        int2 rec = staged[s0 + i];
        recs[i] = rec;
        unsigned int cl = (unsigned)rec.x >> 24;
        atomicAdd(&cnt[cl], 1u);
        atomicAdd(&deg[cl], (unsigned int)rec.y & 0x7FFFu);
    }
    __syncthreads();
    int v = (int)cnt[tid];
    sc[tid] = v;
    __syncthreads();
    for (int off = 1; off < 256; off <<= 1) {
        int add = (tid >= off) ? sc[tid - off] : 0;
        __syncthreads();
        sc[tid] += add;
        __syncthreads();
    }
    int lpre = sc[tid] - v;             // exclusive prefix within bin
    cur[tid] = (unsigned int)lpre;
    int c = b * 256 + tid;
    if (c < N) {
        se[c] = make_int2(s0 + lpre, s0 + lpre + v);
        dinv[c] = rsqrtf(1.0f + (float)deg[tid] * W15_INV);
    }
    __syncthreads();
    for (int i = tid; i < n; i += 256) {   // direct scatter: L2-held window
        int2 rec = recs[i];
        unsigned int cl = (unsigned)rec.x >> 24;
        unsigned int p = atomicAdd(&cur[cl], 1u);
        csr[s0 + p] = (((unsigned int)rec.y & 0x7FFFu) << 17) |
                      ((unsigned)rec.x & 0x1FFFFu);
    }
}

// ------- GEMM (MFMA bf16): t8 = fp8( 16 * dinv .* (x @ W) ), 16 rows/block -------
__global__ __launch_bounds__(256) void k_gemm(const float* __restrict__ x,
                                              const short* __restrict__ WTg,
                                              const float* __restrict__ dinv,
                                              int* __restrict__ th4, int n) {
    __shared__ short Wt[64][72];     // W^T bf16, +8 pad
    __shared__ short xs[16][72];     // x tile bf16
    __shared__ float outs[16][68];   // f32 result bounce for repack
    int tid = threadIdx.x;
    {   // conflict-free staging: lanes write consecutive shorts of a row
        const int* WTi = (const int*)WTg;      // 2048 ints
        for (int i = tid; i < 2048; i += 256)
            *(int*)&Wt[i >> 5][(i & 31) * 2] = WTi[i];
    }
    int row0 = blockIdx.x * 16;
    int nrows = min(16, n - row0);
    {                                             // stage x rows -> bf16
        int r = tid >> 4, c4 = (tid & 15) * 4;
        float4 v = make_float4(0.f, 0.f, 0.f, 0.f);
        if (r < nrows)
            v = ((const float4*)(x + (size_t)(row0 + r) * 64))[tid & 15];
        xs[r][c4 + 0] = (short)f2bf(v.x);
        xs[r][c4 + 1] = (short)f2bf(v.y);
        xs[r][c4 + 2] = (short)f2bf(v.z);
        xs[r][c4 + 3] = (short)f2bf(v.w);
    }
    __syncthreads();
    int wv = tid >> 6, lane = tid & 63;
    int mn = lane & 15, kg = (lane >> 4) * 8;
    f32x4 acc = {0.f, 0.f, 0.f, 0.f};
    short8 a0 = *(const short8*)&xs[mn][kg];
    short8 a1 = *(const short8*)&xs[mn][kg + 32];
    short8 b0 = *(const short8*)&Wt[wv * 16 + mn][kg];
    short8 b1 = *(const short8*)&Wt[wv * 16 + mn][kg + 32];
    acc = __builtin_amdgcn_mfma_f32_16x16x32_bf16(a0, b0, acc, 0, 0, 0);
    acc = __builtin_amdgcn_mfma_f32_16x16x32_bf16(a1, b1, acc, 0, 0, 0);
#pragma unroll
    for (int r = 0; r < 4; ++r)
        outs[(lane >> 4) * 4 + r][wv * 16 + mn] = acc[r];
    __syncthreads();
    int rl = tid >> 4, fq = tid & 15;
    if (rl < nrows) {
        float d = dinv[row0 + rl] * FP8_SCALE;
        float4 o = *(const float4*)&outs[rl][fq * 4];
        int p = __builtin_amdgcn_cvt_pk_fp8_f32(o.x * d, o.y * d, 0, false);
        p = __builtin_amdgcn_cvt_pk_fp8_f32(o.z * d, o.w * d, p, true);
        th4[(row0 + rl) * 16 + fq] = p;
    }
}

// ------- FUSED: gather(th4_in) + ReLU + BN + next-layer GEMM -> th4_out -------
__global__ __launch_bounds__(256) void k_fusedgg(const unsigned int* __restrict__ csr,
                                                 const int2* __restrict__ se,
                                                 const int* __restrict__ th4_in,
                                                 const float* __restrict__ dinv,
                                                 const float* __restrict__ bias,
                                                 const float* __restrict__ gam,
                                                 const float* __restrict__ bet,
                                                 const float* __restrict__ mu,
                                                 const float* __restrict__ var,
                                                 const short* __restrict__ WTg,
                                                 int* __restrict__ th4_out, int n) {
    __shared__ short Wt[64][72];     // next-layer W^T bf16
    __shared__ short xs[16][72];     // h tile bf16 (gather output)
    __shared__ float outs[16][68];   // f32 gemm result bounce
    int tid = threadIdx.x;
    {   // conflict-free staging of pre-transposed W
        const int* WTi = (const int*)WTg;
        for (int i = tid; i < 2048; i += 256)
            *(int*)&Wt[i >> 5][(i & 31) * 2] = WTi[i];
    }
    int nb = xcd_swz(blockIdx.x, gridDim.x);
    int w = tid >> 6;
    int lane = tid & 63;
    int q = lane >> 4;           // quarter -> node owner
    int l = lane & 15;           // feature quad index
    int node = nb * 16 + w * 4 + q;
    bool valid = node < n;
    float4 b4 = ((const float4*)bias)[l];
    float4 m4 = ((const float4*)mu)[l];
    float4 v4 = ((const float4*)var)[l];
    float4 G4 = ((const float4*)gam)[l];
    float4 B4 = ((const float4*)bet)[l];
    float4 scf, shf;
    scf.x = rsqrtf(v4.x + BN_EPS) * G4.x;  shf.x = B4.x - m4.x * scf.x;
    scf.y = rsqrtf(v4.y + BN_EPS) * G4.y;  shf.y = B4.y - m4.y * scf.y;
    scf.z = rsqrtf(v4.z + BN_EPS) * G4.z;  shf.z = B4.z - m4.z * scf.z;
    scf.w = rsqrtf(v4.w + BN_EPS) * G4.w;  shf.w = B4.w - m4.w * scf.w;

    float4 av[4];
    av[0] = make_float4(0.f, 0.f, 0.f, 0.f);
    av[1] = av[0]; av[2] = av[0]; av[3] = av[0];
    float4 sf = av[0];                       // self-loop (weight 1, unscaled)
    int e = 0, eend = 0;
    float dv = 0.f;
    if (valid) {
        int2 ext = se[node];
        e = ext.x; eend = ext.y;
        dv = dinv[node];
        int sv = th4_in[node * 16 + l];
        vfloat2 lo = __builtin_amdgcn_cvt_pk_f32_fp8(sv, false);
        vfloat2 hi = __builtin_amdgcn_cvt_pk_f32_fp8(sv, true);
        sf = make_float4(lo.x, lo.y, hi.x, hi.y);
    }
    while (__any(e < eend)) {
        if (e < eend) {                      // exec-masked: done quarters idle
            unsigned int cc[8];
            int rr[8];
#pragma unroll
            for (int j = 0; j < 8; ++j)      // unclamped: csr has 64B slack,
                cc[j] = __builtin_nontemporal_load(&csr[e + j]);   // wj guards
#pragma unroll
            for (int j = 0; j < 8; ++j)
                rr[j] = th4_in[(int)((cc[j] & 0x1FFFFu) << 4) + l];
#pragma unroll
            for (int j = 0; j < 8; ++j) {
                float wj = (e + j < eend) ? (float)(cc[j] >> 17) : 0.f;
                vfloat2 lo = __builtin_amdgcn_cvt_pk_f32_fp8(rr[j], false);
                vfloat2 hi = __builtin_amdgcn_cvt_pk_f32_fp8(rr[j], true);
                av[j & 3].x = fmaf(wj, lo.x, av[j & 3].x);
                av[j & 3].y = fmaf(wj, lo.y, av[j & 3].y);
                av[j & 3].z = fmaf(wj, hi.x, av[j & 3].z);
                av[j & 3].w = fmaf(wj, hi.y, av[j & 3].w);
            }
        }
        e += 8;
    }
    float4 res = make_float4(0.f, 0.f, 0.f, 0.f);
    if (valid) {
        float4 acc;
        acc.x = ((av[0].x + av[1].x) + (av[2].x + av[3].x)) * W15_INV + sf.x;
        acc.y = ((av[0].y + av[1].y) + (av[2].y + av[3].y)) * W15_INV + sf.y;
        acc.z = ((av[0].z + av[1].z) + (av[2].z + av[3].z)) * W15_INV + sf.z;
        acc.w = ((av[0].w + av[1].w) + (av[2].w + av[3].w)) * W15_INV + sf.w;
        float d = dv * FP8_INV;              // undo table pre-scale
        float r0 = fmaxf(d * acc.x + b4.x, 0.f);   // ReLU then BN
        float r1 = fmaxf(d * acc.y + b4.y, 0.f);
        float r2 = fmaxf(d * acc.z + b4.z, 0.f);
        float r3 = fmaxf(d * acc.w + b4.w, 0.f);
        res.x = r0 * scf.x + shf.x;
        res.y = r1 * scf.y + shf.y;
        res.z = r2 * scf.z + shf.z;
        res.w = r3 * scf.w + shf.w;
    }
    {   // h row -> LDS bf16 (zeros for invalid nodes)
        int nl = w * 4 + q;
        union { unsigned short s[4]; int2 i2; } u;
        u.s[0] = f2bf(res.x); u.s[1] = f2bf(res.y);
        u.s[2] = f2bf(res.z); u.s[3] = f2bf(res.w);
        *(int2*)&xs[nl][4 * l] = u.i2;
    }
    __syncthreads();
    // ------- MFMA gemm on the 16-row h tile -------
    int mn = lane & 15, kg = (lane >> 4) * 8;
    f32x4 acc = {0.f, 0.f, 0.f, 0.f};
    short8 a0 = *(const short8*)&xs[mn][kg];
    short8 a1 = *(const short8*)&xs[mn][kg + 32];
    short8 b0 = *(const short8*)&Wt[w * 16 + mn][kg];
    short8 b1 = *(const short8*)&Wt[w * 16 + mn][kg + 32];
    acc = __builtin_amdgcn_mfma_f32_16x16x32_bf16(a0, b0, acc, 0, 0, 0);
    acc = __builtin_amdgcn_mfma_f32_16x16x32_bf16(a1, b1, acc, 0, 0, 0);
#pragma unroll
    for (int r = 0; r < 4; ++r)
        outs[(lane >> 4) * 4 + r][w * 16 + mn] = acc[r];
    __syncthreads();
    int rl = tid >> 4, fq = tid & 15;
    int row = nb * 16 + rl;
    if (row < n) {
        float d = dinv[row] * FP8_SCALE;
        float4 o = *(const float4*)&outs[rl][fq * 4];
        int p = __builtin_amdgcn_cvt_pk_fp8_f32(o.x * d, o.y * d, 0, false);
        p = __builtin_amdgcn_cvt_pk_fp8_f32(o.z * d, o.w * d, p, true);
        th4_out[row * 16 + fq] = p;
    }
}

// ------- final gather + BN + pool: block-level LDS merge, 8-way spread -------
__global__ __launch_bounds__(256) void k_gather(const unsigned int* __restrict__ csr,
                                                const int2* __restrict__ se,
                                                const int* __restrict__ th4,
                                                const float* __restrict__ dinv,
                                                const float* __restrict__ bias,
                                                const float* __restrict__ gam,
                                                const float* __restrict__ bet,
                                                const float* __restrict__ mu,
                                                const float* __restrict__ var,
                                                const int* __restrict__ batch,
                                                float* __restrict__ pooled8,
                                                int n, int G64) {
    __shared__ float vals[4][64];
    __shared__ int wbid[4];
    int nb = xcd_swz(blockIdx.x, gridDim.x);
    int w = threadIdx.x >> 6;
    int lane = threadIdx.x & 63;
    int q = lane >> 4;           // quarter -> node owner
    int l = lane & 15;           // feature quad index
    int node = nb * 16 + w * 4 + q;
    bool valid = node < n;
    float* myPool = pooled8 + (size_t)(blockIdx.x & (NPOOL - 1)) * G64;
    float4 b4 = ((const float4*)bias)[l];
    float4 m4 = ((const float4*)mu)[l];
    float4 v4 = ((const float4*)var)[l];
    float4 G4 = ((const float4*)gam)[l];
    float4 B4 = ((const float4*)bet)[l];
    float4 scf, shf;
    scf.x = rsqrtf(v4.x + BN_EPS) * G4.x;  shf.x = B4.x - m4.x * scf.x;
    scf.y = rsqrtf(v4.y + BN_EPS) * G4.y;  shf.y = B4.y - m4.y * scf.y;
    scf.z = rsqrtf(v4.z + BN_EPS) * G4.z;  shf.z = B4.z - m4.z * scf.z;
    scf.w = rsqrtf(v4.w + BN_EPS) * G4.w;  shf.w = B4.w - m4.w * scf.w;

    float4 av[4];
    av[0] = make_float4(0.f, 0.f, 0.f, 0.f);
    av[1] = av[0]; av[2] = av[0]; av[3] = av[0];
    float4 sf = av[0];
    int e = 0, eend = 0;
    float dv = 0.f;
    if (valid) {
        int2 ext = se[node];
        e = ext.x; eend = ext.y;
        dv = dinv[node];
        int sv = th4[node * 16 + l];
        vfloat2 lo = __builtin_amdgcn_cvt_pk_f32_fp8(sv, false);
        vfloat2 hi = __builtin_amdgcn_cvt_pk_f32_fp8(sv, true);
        sf = make_float4(lo.x, lo.y, hi.x, hi.y);
    }
    while (__any(e < eend)) {
        if (e < eend) {
            unsigned int cc[8];
            int rr[8];
#pragma unroll
            for (int j = 0; j < 8; ++j)
                cc[j] = __builtin_nontemporal_load(&csr[e + j]);
#pragma unroll
            for (int j = 0; j < 8; ++j)
                rr[j] = th4[(int)((cc[j] & 0x1FFFFu) << 4) + l];
#pragma unroll
            for (int j = 0; j < 8; ++j) {
                float wj = (e + j < eend) ? (float)(cc[j] >> 17) : 0.f;
                vfloat2 lo = __builtin_amdgcn_cvt_pk_f32_fp8(rr[j], false);
                vfloat2 hi = __builtin_amdgcn_cvt_pk_f32_fp8(rr[j], true);
                av[j & 3].x = fmaf(wj, lo.x, av[j & 3].x);
                av[j & 3].y = fmaf(wj, lo.y, av[j & 3].y);
                av[j & 3].z = fmaf(wj, hi.x, av[j & 3].z);
                av[j & 3].w = fmaf(wj, hi.y, av[j & 3].w);
            }
        }
        e += 8;
    }
    float4 res = make_float4(0.f, 0.f, 0.f, 0.f);
    if (valid) {
        float4 acc;
        acc.x = ((av[0].x + av[1].x) + (av[2].x + av[3].x)) * W15_INV + sf.x;
        acc.y = ((av[0].y + av[1].y) + (av[2].y + av[3].y)) * W15_INV + sf.y;
        acc.z = ((av[0].z + av[1].z) + (av[2].z + av[3].z)) * W15_INV + sf.z;
        acc.w = ((av[0].w + av[1].w) + (av[2].w + av[3].w)) * W15_INV + sf.w;
        float d = dv * FP8_INV;
        float r0 = d * acc.x + b4.x;         // no ReLU before bn3
        float r1 = d * acc.y + b4.y;
        float r2 = d * acc.z + b4.z;
        float r3 = d * acc.w + b4.w;
        res.x = r0 * scf.x + shf.x;
        res.y = r1 * scf.y + shf.y;
        res.z = r2 * scf.z + shf.z;
        res.w = r3 * scf.w + shf.w;
    }
    int bid = valid ? batch[node] : -1;
    int bid0 = __shfl(bid, 0);
    bool same = __all(bid == bid0);
    if (same) {                              // common: wave's 4 nodes one graph
        res.x += __shfl_xor(res.x, 16);
        res.y += __shfl_xor(res.y, 16);
        res.z += __shfl_xor(res.z, 16);
        res.w += __shfl_xor(res.w, 16);
        res.x += __shfl_xor(res.x, 32);
        res.y += __shfl_xor(res.y, 32);
        res.z += __shfl_xor(res.z, 32);
        res.w += __shfl_xor(res.w, 32);
        if (q == 0) ((float4*)&vals[w][0])[l] = res;
        if (lane == 0) wbid[w] = bid0;       // may be -1 if wave invalid
    } else {
        if (valid) {                         // rare boundary wave: direct flush
            float* pp = myPool + bid * 64 + 4 * l;
            fatomic_add(pp + 0, res.x);
            fatomic_add(pp + 1, res.y);
            fatomic_add(pp + 2, res.z);
            fatomic_add(pp + 3, res.w);
        }
        if (lane == 0) wbid[w] = -1;         // nothing in LDS for this wave
    }
    __syncthreads();
    if (w == 0) {                            // wave 0: merge 4 wave-partials
        int f = threadIdx.x;                 // 0..63
        float s2 = 0.f;
        int cur = -1;
#pragma unroll
        for (int i = 0; i < 4; ++i) {
            int bi = wbid[i];
            if (bi < 0) continue;
            if (bi == cur) {
                s2 += vals[i][f];
            } else {
                if (cur >= 0) fatomic_add(&myPool[cur * 64 + f], s2);
                cur = bi;
                s2 = vals[i][f];
            }
        }
        if (cur >= 0) fatomic_add(&myPool[cur * 64 + f], s2);
    }
}

// ---- final: out[g] = ReLU(sum_8 pooled8[g]) @ Wfc + bfc (block per graph) ----
__global__ __launch_bounds__(64) void k_fc(const float* __restrict__ pooled8,
                                           const float* __restrict__ Wfc,
                                           const float* __restrict__ bfc,
                                           float* __restrict__ out, int G) {
    int g = blockIdx.x;
    int f = threadIdx.x;         // 0..63
    int G64 = G * 64;
    float p = 0.f;
#pragma unroll
    for (int c = 0; c < NPOOL; ++c) p += pooled8[c * G64 + g * 64 + f];
    float s = fmaxf(p, 0.f) * Wfc[f];
#pragma unroll
    for (int off = 1; off < 64; off <<= 1) s += __shfl_xor(s, off);
    if (f == 0) out[g] = s + bfc[0];
}

extern "C" void kernel_launch(void* const* d_in, const int* in_sizes, int n_in,
                              void* d_out, int out_size, void* d_ws, size_t ws_size,
                              hipStream_t stream) {
    const float* x    = (const float*)d_in[0];
    const int*   eidx = (const int*)d_in[1];
    const float* ew   = (const float*)d_in[2];
    const int*   batch= (const int*)d_in[3];
    const float* W1 = (const float*)d_in[4];
    const float* b1 = (const float*)d_in[5];
    const float* W2 = (const float*)d_in[6];
    const float* b2 = (const float*)d_in[7];
    const float* W3 = (const float*)d_in[8];
    const float* b3 = (const float*)d_in[9];
    const float* Wfc = (const float*)d_in[10];
    const float* bfc = (const float*)d_in[11];
    const float* g1 = (const float*)d_in[12];
    const float* be1 = (const float*)d_in[13];
    const float* m1 = (const float*)d_in[14];
    const float* v1 = (const float*)d_in[15];
    const float* g2 = (const float*)d_in[16];
    const float* be2 = (const float*)d_in[17];
    const float* m2 = (const float*)d_in[18];
    const float* v2 = (const float*)d_in[19];
    const float* g3 = (const float*)d_in[20];
    const float* be3 = (const float*)d_in[21];
    const float* m3 = (const float*)d_in[22];
    const float* v3 = (const float*)d_in[23];

    const int N = in_sizes[0] / 64;     // 100000
    const int E = in_sizes[1] / 2;      // 1600000
    const int G = out_size;             // 128
    const int* rowi = eidx;
    const int* coli = eidx + E;
    const int NB = (N + 255) >> 8;      // 391 destination bins

    // -------- workspace layout (256B aligned) --------
    char* ws = (char*)d_ws;
    size_t off = 0;
    auto alloc = [&](size_t bytes) {
        char* p = ws + off;
        off += (bytes + 255) & ~(size_t)255;
        return p;
    };
    unsigned int* binCursor = (unsigned int*)alloc(512 * 4);
    float* dinv   = (float*)alloc((size_t)N * 4);
    int2*  se     = (int2*) alloc((size_t)N * 8);
    unsigned int* csr = (unsigned int*)alloc((size_t)NB * PADCAP * 4 + 256);
    int*   th4a   = (int*)  alloc((size_t)N * 64);        // fp8 table ping
    int*   th4b   = (int*)  alloc((size_t)N * 64);        // fp8 table pong
    float* pooled8 = (float*)alloc((size_t)NPOOL * G * 64 * 4);
    short* wtg    = (short*)alloc(3 * 4096 * 2);          // W1T/W2T/W3T bf16
    int2*  staged = (int2*)alloc((size_t)NB * PADCAP * 8);

    const int bblk = (E + EPB - 1) / EPB;   // 391
    const int gblk = (N + 15) / 16;         // 6250: 16 nodes/block (4/wave)
    const int mblk = (N + 15) / 16;

    // -------- binned CSR build + normalization + W^T (2 kernels) --------
    hipMemsetAsync(binCursor, 0, 512 * 4, stream);
    k_binscatter<<<bblk, 256, 0, stream>>>(rowi, coli, ew, binCursor, staged,
                                           pooled8, W1, W2, W3, wtg,
                                           E, NB, NPOOL * G * 64);
    k_binfinal<<<NB, 256, 0, stream>>>(staged, binCursor, csr, se, dinv, N);

    // -------- layer 1 gemm --------
    k_gemm<<<mblk, 256, 0, stream>>>(x, wtg, dinv, th4a, N);
    // -------- gather1 + BN1 + gemm2 (fused) --------
    k_fusedgg<<<gblk, 256, 0, stream>>>(csr, se, th4a, dinv, b1, g1, be1, m1, v1,
                                        wtg + 4096, th4b, N);
    // -------- gather2 + BN2 + gemm3 (fused) --------
    k_fusedgg<<<gblk, 256, 0, stream>>>(csr, se, th4b, dinv, b2, g2, be2, m2, v2,
                                        wtg + 8192, th4a, N);
    // -------- gather3 + BN3 + pool (block-merged atomics) --------
    k_gather<<<gblk, 256, 0, stream>>>(csr, se, th4a, dinv, b3, g3, be3, m3, v3,
                                       batch, pooled8, N, G * 64);
    // -------- FC head --------
    k_fc<<<G, 64, 0, stream>>>(pooled8, Wfc, bfc, (float*)d_out, G);
}

// Round 12
// 295.869 us; speedup vs baseline: 1.2621x; 1.0013x over previous
//
#include <hip/hip_runtime.h>
#include <hip/hip_fp16.h>

#define BN_EPS 1e-5f
#define EPB 4096                 // edges per block in bin passes
#define PADCAP 4608              // per-bin capacity (mean 4096 + 8 sigma)
#define FP8_SCALE 16.0f          // table pre-scale: e4m3 sweet band, no denormals
#define FP8_INV (1.0f / 16.0f)
#define W15_INV (1.0f / 32768.0f)
#define NPOOL 8                  // pooled replicas (contention spread)

typedef __attribute__((ext_vector_type(2))) float vfloat2;
typedef __attribute__((ext_vector_type(8))) short short8;   // 8 x bf16 frag
typedef __attribute__((ext_vector_type(4))) float f32x4;

__device__ __forceinline__ float fatomic_add(float* p, float v) {
    return unsafeAtomicAdd(p, v);  // HW global_atomic_add_f32
}

__device__ __forceinline__ unsigned short f2bf(float f) {   // f32 -> bf16 (RNE-ish)
    unsigned int u = __float_as_uint(f);
    return (unsigned short)((u + 0x7FFFu + ((u >> 16) & 1u)) >> 16);
}

// m204 bijective XCD-chunked swizzle: consecutive logical blocks -> same XCD
__device__ __forceinline__ int xcd_swz(int bid, int nwg) {
    int xcd = bid & 7, k = bid >> 3;
    int q = nwg >> 3, r = nwg & 7;
    return (xcd < r ? xcd * (q + 1) : r * (q + 1) + (xcd - r) * q) + k;
}

// ---------- B1: bin-sorted scatter into padded bin staging (512 thr) ----------
// Records counting-sorted by bin in LDS first -> contiguous ~84B runs per bin
// on the global dump. 512 threads halve the per-block serial phases (391-block
// launch is straggler-latency-bound, not BW-bound).
// staged rec: x = src | (c_local << 24), y = w15 | (bin << 15)
// block 0 zeroes pooled8; block 1 builds the bf16 W^T tables
__global__ __launch_bounds__(512) void k_binscatter(const int* __restrict__ rowi,
                                                    const int* __restrict__ coli,
                                                    const float* __restrict__ ew,
                                                    unsigned int* __restrict__ binCursor,
                                                    int2* __restrict__ staged,
                                                    float* __restrict__ pooled8,
                                                    const float* __restrict__ W1,
                                                    const float* __restrict__ W2,
                                                    const float* __restrict__ W3,
                                                    short* __restrict__ WT,
                                                    int E, int NB, int PZ) {
    __shared__ unsigned int h[512];      // per-bin counts
    __shared__ unsigned int lo[512];     // exclusive prefix (local offsets)
    __shared__ unsigned int dd[512];     // global dump delta per bin
    __shared__ unsigned int ps[256];     // pair-sum scan buffer
    __shared__ int2 lsorted[EPB];        // 32KB bin-sorted records
    int tid = threadIdx.x;
    if (blockIdx.x == 0) {
        for (int i = tid; i < PZ; i += 512) pooled8[i] = 0.f;
    } else if (blockIdx.x == 1) {              // fold W pre-transpose here
        const float* Wm[3] = {W1, W2, W3};
#pragma unroll
        for (int m = 0; m < 3; ++m) {
            const float* W = Wm[m];
            short* o = WT + m * 4096;
            for (int i = tid; i < 4096; i += 512)
                o[i] = (short)f2bf(W[(i & 63) * 64 + (i >> 6)]);
        }
    }
    h[tid] = 0;
    __syncthreads();
    int base = blockIdx.x * EPB;
    int lim = min(EPB, E - base);
    unsigned short rank[8];
    int nj = (lim - tid + 511) / 512;           // iterations this thread runs
    for (int j = 0; j < nj; ++j) {
        int e = base + tid + j * 512;
        rank[j] = (unsigned short)atomicAdd(&h[(unsigned)coli[e] >> 8], 1u);
    }
    __syncthreads();
    // exclusive prefix over 512 bins: 256 scan lanes, uniform barriers
    unsigned int a0 = 0, a1 = 0;
    if (tid < 256) { a0 = h[2 * tid]; a1 = h[2 * tid + 1]; ps[tid] = a0 + a1; }
    __syncthreads();
    for (int off = 1; off < 256; off <<= 1) {
        unsigned int add = (tid >= off && tid < 256) ? ps[tid - off] : 0u;
        __syncthreads();
        if (tid < 256) ps[tid] += add;
        __syncthreads();
    }
    if (tid < 256) {
        unsigned int excl = ps[tid] - (a0 + a1);
        lo[2 * tid] = excl;
        lo[2 * tid + 1] = excl + a0;
    }
    __syncthreads();
    for (int b = tid; b < NB; b += 512) {       // reserve global + dump delta
        unsigned int bbv = h[b] ? atomicAdd(&binCursor[b], h[b]) : 0u;
        dd[b] = (unsigned int)(b * PADCAP) + bbv - lo[b];
    }
    __syncthreads();
    for (int j = 0; j < nj; ++j) {              // scatter into sorted LDS
        int e = base + tid + j * 512;
        unsigned int c = (unsigned)coli[e];
        unsigned int b = c >> 8;
        int2 rec;
        rec.x = rowi[e] | (int)((c & 255u) << 24);
        unsigned int w15 = min((unsigned int)(ew[e] * 32768.f + 0.5f), 32767u);
        rec.y = (int)(w15 | (b << 15));
        lsorted[lo[b] + rank[j]] = rec;
    }
    __syncthreads();
    for (int i = tid; i < lim; i += 512) {      // contiguous per-bin runs out
        int2 rec = lsorted[i];
        unsigned int b = ((unsigned)rec.y >> 15) & 0x1FFu;
        staged[dd[b] + i] = rec;
    }
}

// ---------- B2: per-bin LDS counting sort -> csr(4B recs), se, dinv (1024 thr) ----------
// csr record: (w15 << 17) | src   (staged rec.y carries bin bits: mask 0x7FFF)
// 1024 threads cut the strided load/scatter phases 16 -> 5 iterations.
__global__ __launch_bounds__(1024) void k_binfinal(const int2* __restrict__ staged,
                                                   const unsigned int* __restrict__ binCursor,
                                                   unsigned int* __restrict__ csr,
                                                   int2* __restrict__ se,
                                                   float* __restrict__ dinv,
                                                   int N) {
    __shared__ int2 recs[PADCAP];
    __shared__ unsigned int cnt[256];
    __shared__ unsigned int deg[256];   // integer sum of w15
    __shared__ int sc[256];
    __shared__ unsigned int cur[256];
    int tid = threadIdx.x;
    int b = blockIdx.x;
    int s0 = b * PADCAP;
    int n = (int)binCursor[b];          // actual bin count
    if (tid < 256) { cnt[tid] = 0; deg[tid] = 0; }
    __syncthreads();
    for (int i = tid; i < n; i += 1024) {
        int2 rec = staged[s0 + i];
        recs[i] = rec;
        unsigned int cl = (unsigned)rec.x >> 24;
        atomicAdd(&cnt[cl], 1u);
        atomicAdd(&deg[cl], (unsigned int)rec.y & 0x7FFFu);
    }
    __syncthreads();
    int v = 0;
    if (tid < 256) { v = (int)cnt[tid]; sc[tid] = v; }
    __syncthreads();
    for (int off = 1; off < 256; off <<= 1) {
        int add = (tid >= off && tid < 256) ? sc[tid - off] : 0;
        __syncthreads();
        if (tid < 256) sc[tid] += add;
        __syncthreads();
    }
    if (tid < 256) {
        int lpre = sc[tid] - v;         // exclusive prefix within bin
        cur[tid] = (unsigned int)lpre;
        int c = b * 256 + tid;
        if (c < N) {
            se[c] = make_int2(s0 + lpre, s0 + lpre + v);
            dinv[c] = rsqrtf(1.0f + (float)deg[tid] * W15_INV);
        }
    }
    __syncthreads();
    for (int i = tid; i < n; i += 1024) {  // direct scatter: L2-held window
        int2 rec = recs[i];
        unsigned int cl = (unsigned)rec.x >> 24;
        unsigned int p = atomicAdd(&cur[cl], 1u);
        csr[s0 + p] = (((unsigned int)rec.y & 0x7FFFu) << 17) |
                      ((unsigned)rec.x & 0x1FFFFu);
    }
}

// ------- GEMM (MFMA bf16): t8 = fp8( 16 * dinv .* (x @ W) ), 16 rows/block -------
__global__ __launch_bounds__(256) void k_gemm(const float* __restrict__ x,
                                              const short* __restrict__ WTg,
                                              const float* __restrict__ dinv,
                                              int* __restrict__ th4, int n) {
    __shared__ short Wt[64][72];     // W^T bf16, +8 pad
    __shared__ short xs[16][72];     // x tile bf16
    __shared__ float outs[16][68];   // f32 result bounce for repack
    int tid = threadIdx.x;
    {   // conflict-free staging: lanes write consecutive shorts of a row
        const int* WTi = (const int*)WTg;      // 2048 ints
        for (int i = tid; i < 2048; i += 256)
            *(int*)&Wt[i >> 5][(i & 31) * 2] = WTi[i];
    }
    int row0 = blockIdx.x * 16;
    int nrows = min(16, n - row0);
    {                                             // stage x rows -> bf16
        int r = tid >> 4, c4 = (tid & 15) * 4;
        float4 v = make_float4(0.f, 0.f, 0.f, 0.f);
        if (r < nrows)
            v = ((const float4*)(x + (size_t)(row0 + r) * 64))[tid & 15];
        xs[r][c4 + 0] = (short)f2bf(v.x);
        xs[r][c4 + 1] = (short)f2bf(v.y);
        xs[r][c4 + 2] = (short)f2bf(v.z);
        xs[r][c4 + 3] = (short)f2bf(v.w);
    }
    __syncthreads();
    int wv = tid >> 6, lane = tid & 63;
    int mn = lane & 15, kg = (lane >> 4) * 8;
    f32x4 acc = {0.f, 0.f, 0.f, 0.f};
    short8 a0 = *(const short8*)&xs[mn][kg];
    short8 a1 = *(const short8*)&xs[mn][kg + 32];
    short8 b0 = *(const short8*)&Wt[wv * 16 + mn][kg];
    short8 b1 = *(const short8*)&Wt[wv * 16 + mn][kg + 32];
    acc = __builtin_amdgcn_mfma_f32_16x16x32_bf16(a0, b0, acc, 0, 0, 0);
    acc = __builtin_amdgcn_mfma_f32_16x16x32_bf16(a1, b1, acc, 0, 0, 0);
#pragma unroll
    for (int r = 0; r < 4; ++r)
        outs[(lane >> 4) * 4 + r][wv * 16 + mn] = acc[r];
    __syncthreads();
    int rl = tid >> 4, fq = tid & 15;
    if (rl < nrows) {
        float d = dinv[row0 + rl] * FP8_SCALE;
        float4 o = *(const float4*)&outs[rl][fq * 4];
        int p = __builtin_amdgcn_cvt_pk_fp8_f32(o.x * d, o.y * d, 0, false);
        p = __builtin_amdgcn_cvt_pk_fp8_f32(o.z * d, o.w * d, p, true);
        th4[(row0 + rl) * 16 + fq] = p;
    }
}

// ------- FUSED: gather(th4_in) + ReLU + BN + next-layer GEMM -> th4_out -------
__global__ __launch_bounds__(256) void k_fusedgg(const unsigned int* __restrict__ csr,
                                                 const int2* __restrict__ se,
                                                 const int* __restrict__ th4_in,
                                                 const float* __restrict__ dinv,
                                                 const float* __restrict__ bias,
                                                 const float* __restrict__ gam,
                                                 const float* __restrict__ bet,
                                                 const float* __restrict__ mu,
                                                 const float* __restrict__ var,
                                                 const short* __restrict__ WTg,
                                                 int* __restrict__ th4_out, int n) {
    __shared__ short Wt[64][72];     // next-layer W^T bf16
    __shared__ short xs[16][72];     // h tile bf16 (gather output)
    __shared__ float outs[16][68];   // f32 gemm result bounce
    int tid = threadIdx.x;
    {   // conflict-free staging of pre-transposed W
        const int* WTi = (const int*)WTg;
        for (int i = tid; i < 2048; i += 256)
            *(int*)&Wt[i >> 5][(i & 31) * 2] = WTi[i];
    }
    int nb = xcd_swz(blockIdx.x, gridDim.x);
    int w = tid >> 6;
    int lane = tid & 63;
    int q = lane >> 4;           // quarter -> node owner
    int l = lane & 15;           // feature quad index
    int node = nb * 16 + w * 4 + q;
    bool valid = node < n;
    float4 b4 = ((const float4*)bias)[l];
    float4 m4 = ((const float4*)mu)[l];
    float4 v4 = ((const float4*)var)[l];
    float4 G4 = ((const float4*)gam)[l];
    float4 B4 = ((const float4*)bet)[l];
    float4 scf, shf;
    scf.x = rsqrtf(v4.x + BN_EPS) * G4.x;  shf.x = B4.x - m4.x * scf.x;
    scf.y = rsqrtf(v4.y + BN_EPS) * G4.y;  shf.y = B4.y - m4.y * scf.y;
    scf.z = rsqrtf(v4.z + BN_EPS) * G4.z;  shf.z = B4.z - m4.z * scf.z;
    scf.w = rsqrtf(v4.w + BN_EPS) * G4.w;  shf.w = B4.w - m4.w * scf.w;

    float4 av[4];
    av[0] = make_float4(0.f, 0.f, 0.f, 0.f);
    av[1] = av[0]; av[2] = av[0]; av[3] = av[0];
    float4 sf = av[0];                       // self-loop (weight 1, unscaled)
    int e = 0, eend = 0;
    float dv = 0.f;
    if (valid) {
        int2 ext = se[node];
        e = ext.x; eend = ext.y;
        dv = dinv[node];
        int sv = th4_in[node * 16 + l];
        vfloat2 lo = __builtin_amdgcn_cvt_pk_f32_fp8(sv, false);
        vfloat2 hi = __builtin_amdgcn_cvt_pk_f32_fp8(sv, true);
        sf = make_float4(lo.x, lo.y, hi.x, hi.y);
    }
    while (__any(e < eend)) {
        if (e < eend) {                      // exec-masked: done quarters idle
            unsigned int cc[8];
            int rr[8];
#pragma unroll
            for (int j = 0; j < 8; ++j)      // unclamped: csr has 64B slack,
                cc[j] = __builtin_nontemporal_load(&csr[e + j]);   // wj guards
#pragma unroll
            for (int j = 0; j < 8; ++j)
                rr[j] = th4_in[(int)((cc[j] & 0x1FFFFu) << 4) + l];
#pragma unroll
            for (int j = 0; j < 8; ++j) {
                float wj = (e + j < eend) ? (float)(cc[j] >> 17) : 0.f;
                vfloat2 lo = __builtin_amdgcn_cvt_pk_f32_fp8(rr[j], false);
                vfloat2 hi = __builtin_amdgcn_cvt_pk_f32_fp8(rr[j], true);
                av[j & 3].x = fmaf(wj, lo.x, av[j & 3].x);
                av[j & 3].y = fmaf(wj, lo.y, av[j & 3].y);
                av[j & 3].z = fmaf(wj, hi.x, av[j & 3].z);
                av[j & 3].w = fmaf(wj, hi.y, av[j & 3].w);
            }
        }
        e += 8;
    }
    float4 res = make_float4(0.f, 0.f, 0.f, 0.f);
    if (valid) {
        float4 acc;
        acc.x = ((av[0].x + av[1].x) + (av[2].x + av[3].x)) * W15_INV + sf.x;
        acc.y = ((av[0].y + av[1].y) + (av[2].y + av[3].y)) * W15_INV + sf.y;
        acc.z = ((av[0].z + av[1].z) + (av[2].z + av[3].z)) * W15_INV + sf.z;
        acc.w = ((av[0].w + av[1].w) + (av[2].w + av[3].w)) * W15_INV + sf.w;
        float d = dv * FP8_INV;              // undo table pre-scale
        float r0 = fmaxf(d * acc.x + b4.x, 0.f);   // ReLU then BN
        float r1 = fmaxf(d * acc.y + b4.y, 0.f);
        float r2 = fmaxf(d * acc.z + b4.z, 0.f);
        float r3 = fmaxf(d * acc.w + b4.w, 0.f);
        res.x = r0 * scf.x + shf.x;
        res.y = r1 * scf.y + shf.y;
        res.z = r2 * scf.z + shf.z;
        res.w = r3 * scf.w + shf.w;
    }
    {   // h row -> LDS bf16 (zeros for invalid nodes)
        int nl = w * 4 + q;
        union { unsigned short s[4]; int2 i2; } u;
        u.s[0] = f2bf(res.x); u.s[1] = f2bf(res.y);
        u.s[2] = f2bf(res.z); u.s[3] = f2bf(res.w);
        *(int2*)&xs[nl][4 * l] = u.i2;
    }
    __syncthreads();
    // ------- MFMA gemm on the 16-row h tile -------
    int mn = lane & 15, kg = (lane >> 4) * 8;
    f32x4 acc = {0.f, 0.f, 0.f, 0.f};
    short8 a0 = *(const short8*)&xs[mn][kg];
    short8 a1 = *(const short8*)&xs[mn][kg + 32];
    short8 b0 = *(const short8*)&Wt[w * 16 + mn][kg];
    short8 b1 = *(const short8*)&Wt[w * 16 + mn][kg + 32];
    acc = __builtin_amdgcn_mfma_f32_16x16x32_bf16(a0, b0, acc, 0, 0, 0);
    acc = __builtin_amdgcn_mfma_f32_16x16x32_bf16(a1, b1, acc, 0, 0, 0);
#pragma unroll
    for (int r = 0; r < 4; ++r)
        outs[(lane >> 4) * 4 + r][w * 16 + mn] = acc[r];
    __syncthreads();
    int rl = tid >> 4, fq = tid & 15;
    int row = nb * 16 + rl;
    if (row < n) {
        float d = dinv[row] * FP8_SCALE;
        float4 o = *(const float4*)&outs[rl][fq * 4];
        int p = __builtin_amdgcn_cvt_pk_fp8_f32(o.x * d, o.y * d, 0, false);
        p = __builtin_amdgcn_cvt_pk_fp8_f32(o.z * d, o.w * d, p, true);
        th4_out[row * 16 + fq] = p;
    }
}

// ------- final gather + BN + pool: block-level LDS merge, 8-way spread -------
__global__ __launch_bounds__(256) void k_gather(const unsigned int* __restrict__ csr,
                                                const int2* __restrict__ se,
                                                const int* __restrict__ th4,
                                                const float* __restrict__ dinv,
                                                const float* __restrict__ bias,
                                                const float* __restrict__ gam,
                                                const float* __restrict__ bet,
                                                const float* __restrict__ mu,
                                                const float* __restrict__ var,
                                                const int* __restrict__ batch,
                                                float* __restrict__ pooled8,
                                                int n, int G64) {
    __shared__ float vals[4][64];
    __shared__ int wbid[4];
    int nb = xcd_swz(blockIdx.x, gridDim.x);
    int w = threadIdx.x >> 6;
    int lane = threadIdx.x & 63;
    int q = lane >> 4;           // quarter -> node owner
    int l = lane & 15;           // feature quad index
    int node = nb * 16 + w * 4 + q;
    bool valid = node < n;
    float* myPool = pooled8 + (size_t)(blockIdx.x & (NPOOL - 1)) * G64;
    float4 b4 = ((const float4*)bias)[l];
    float4 m4 = ((const float4*)mu)[l];
    float4 v4 = ((const float4*)var)[l];
    float4 G4 = ((const float4*)gam)[l];
    float4 B4 = ((const float4*)bet)[l];
    float4 scf, shf;
    scf.x = rsqrtf(v4.x + BN_EPS) * G4.x;  shf.x = B4.x - m4.x * scf.x;
    scf.y = rsqrtf(v4.y + BN_EPS) * G4.y;  shf.y = B4.y - m4.y * scf.y;
    scf.z = rsqrtf(v4.z + BN_EPS) * G4.z;  shf.z = B4.z - m4.z * scf.z;
    scf.w = rsqrtf(v4.w + BN_EPS) * G4.w;  shf.w = B4.w - m4.w * scf.w;

    float4 av[4];
    av[0] = make_float4(0.f, 0.f, 0.f, 0.f);
    av[1] = av[0]; av[2] = av[0]; av[3] = av[0];
    float4 sf = av[0];
    int e = 0, eend = 0;
    float dv = 0.f;
    if (valid) {
        int2 ext = se[node];
        e = ext.x; eend = ext.y;
        dv = dinv[node];
        int sv = th4[node * 16 + l];
        vfloat2 lo = __builtin_amdgcn_cvt_pk_f32_fp8(sv, false);
        vfloat2 hi = __builtin_amdgcn_cvt_pk_f32_fp8(sv, true);
        sf = make_float4(lo.x, lo.y, hi.x, hi.y);
    }
    while (__any(e < eend)) {
        if (e < eend) {
            unsigned int cc[8];
            int rr[8];
#pragma unroll
            for (int j = 0; j < 8; ++j)
                cc[j] = __builtin_nontemporal_load(&csr[e + j]);
#pragma unroll
            for (int j = 0; j < 8; ++j)
                rr[j] = th4[(int)((cc[j] & 0x1FFFFu) << 4) + l];
#pragma unroll
            for (int j = 0; j < 8; ++j) {
                float wj = (e + j < eend) ? (float)(cc[j] >> 17) : 0.f;
                vfloat2 lo = __builtin_amdgcn_cvt_pk_f32_fp8(rr[j], false);
                vfloat2 hi = __builtin_amdgcn_cvt_pk_f32_fp8(rr[j], true);
                av[j & 3].x = fmaf(wj, lo.x, av[j & 3].x);
                av[j & 3].y = fmaf(wj, lo.y, av[j & 3].y);
                av[j & 3].z = fmaf(wj, hi.x, av[j & 3].z);
                av[j & 3].w = fmaf(wj, hi.y, av[j & 3].w);
            }
        }
        e += 8;
    }
    float4 res = make_float4(0.f, 0.f, 0.f, 0.f);
    if (valid) {
        float4 acc;
        acc.x = ((av[0].x + av[1].x) + (av[2].x + av[3].x)) * W15_INV + sf.x;
        acc.y = ((av[0].y + av[1].y) + (av[2].y + av[3].y)) * W15_INV + sf.y;
        acc.z = ((av[0].z + av[1].z) + (av[2].z + av[3].z)) * W15_INV + sf.z;
        acc.w = ((av[0].w + av[1].w) + (av[2].w + av[3].w)) * W15_INV + sf.w;
        float d = dv * FP8_INV;
        float r0 = d * acc.x + b4.x;         // no ReLU before bn3
        float r1 = d * acc.y + b4.y;
        float r2 = d * acc.z + b4.z;
        float r3 = d * acc.w + b4.w;
        res.x = r0 * scf.x + shf.x;
        res.y = r1 * scf.y + shf.y;
        res.z = r2 * scf.z + shf.z;
        res.w = r3 * scf.w + shf.w;
    }
    int bid = valid ? batch[node] : -1;
    int bid0 = __shfl(bid, 0);
    bool same = __all(bid == bid0);
    if (same) {                              // common: wave's 4 nodes one graph
        res.x += __shfl_xor(res.x, 16);
        res.y += __shfl_xor(res.y, 16);
        res.z += __shfl_xor(res.z, 16);
        res.w += __shfl_xor(res.w, 16);
        res.x += __shfl_xor(res.x, 32);
        res.y += __shfl_xor(res.y, 32);
        res.z += __shfl_xor(res.z, 32);
        res.w += __shfl_xor(res.w, 32);
        if (q == 0) ((float4*)&vals[w][0])[l] = res;
        if (lane == 0) wbid[w] = bid0;       // may be -1 if wave invalid
    } else {
        if (valid) {                         // rare boundary wave: direct flush
            float* pp = myPool + bid * 64 + 4 * l;
            fatomic_add(pp + 0, res.x);
            fatomic_add(pp + 1, res.y);
            fatomic_add(pp + 2, res.z);
            fatomic_add(pp + 3, res.w);
        }
        if (lane == 0) wbid[w] = -1;         // nothing in LDS for this wave
    }
    __syncthreads();
    if (w == 0) {                            // wave 0: merge 4 wave-partials
        int f = threadIdx.x;                 // 0..63
        float s2 = 0.f;
        int cur = -1;
#pragma unroll
        for (int i = 0; i < 4; ++i) {
            int bi = wbid[i];
            if (bi < 0) continue;
            if (bi == cur) {
                s2 += vals[i][f];
            } else {
                if (cur >= 0) fatomic_add(&myPool[cur * 64 + f], s2);
                cur = bi;
                s2 = vals[i][f];
            }
        }
        if (cur >= 0) fatomic_add(&myPool[cur * 64 + f], s2);
    }
}

// ---- final: out[g] = ReLU(sum_8 pooled8[g]) @ Wfc + bfc (block per graph) ----
__global__ __launch_bounds__(64) void k_fc(const float* __restrict__ pooled8,
                                           const float* __restrict__ Wfc,
                                           const float* __restrict__ bfc,
                                           float* __restrict__ out, int G) {
    int g = blockIdx.x;
    int f = threadIdx.x;         // 0..63
    int G64 = G * 64;
    float p = 0.f;
#pragma unroll
    for (int c = 0; c < NPOOL; ++c) p += pooled8[c * G64 + g * 64 + f];
    float s = fmaxf(p, 0.f) * Wfc[f];
#pragma unroll
    for (int off = 1; off < 64; off <<= 1) s += __shfl_xor(s, off);
    if (f == 0) out[g] = s + bfc[0];
}

extern "C" void kernel_launch(void* const* d_in, const int* in_sizes, int n_in,
                              void* d_out, int out_size, void* d_ws, size_t ws_size,
                              hipStream_t stream) {
    const float* x    = (const float*)d_in[0];
    const int*   eidx = (const int*)d_in[1];
    const float* ew   = (const float*)d_in[2];
    const int*   batch= (const int*)d_in[3];
    const float* W1 = (const float*)d_in[4];
    const float* b1 = (const float*)d_in[5];
    const float* W2 = (const float*)d_in[6];
    const float* b2 = (const float*)d_in[7];
    const float* W3 = (const float*)d_in[8];
    const float* b3 = (const float*)d_in[9];
    const float* Wfc = (const float*)d_in[10];
    const float* bfc = (const float*)d_in[11];
    const float* g1 = (const float*)d_in[12];
    const float* be1 = (const float*)d_in[13];
    const float* m1 = (const float*)d_in[14];
    const float* v1 = (const float*)d_in[15];
    const float* g2 = (const float*)d_in[16];
    const float* be2 = (const float*)d_in[17];
    const float* m2 = (const float*)d_in[18];
    const float* v2 = (const float*)d_in[19];
    const float* g3 = (const float*)d_in[20];
    const float* be3 = (const float*)d_in[21];
    const float* m3 = (const float*)d_in[22];
    const float* v3 = (const float*)d_in[23];

    const int N = in_sizes[0] / 64;     // 100000
    const int E = in_sizes[1] / 2;      // 1600000
    const int G = out_size;             // 128
    const int* rowi = eidx;
    const int* coli = eidx + E;
    const int NB = (N + 255) >> 8;      // 391 destination bins

    // -------- workspace layout (256B aligned) --------
    char* ws = (char*)d_ws;
    size_t off = 0;
    auto alloc = [&](size_t bytes) {
        char* p = ws + off;
        off += (bytes + 255) & ~(size_t)255;
        return p;
    };
    unsigned int* binCursor = (unsigned int*)alloc(512 * 4);
    float* dinv   = (float*)alloc((size_t)N * 4);
    int2*  se     = (int2*) alloc((size_t)N * 8);
    unsigned int* csr = (unsigned int*)alloc((size_t)NB * PADCAP * 4 + 256);
    int*   th4a   = (int*)  alloc((size_t)N * 64);        // fp8 table ping
    int*   th4b   = (int*)  alloc((size_t)N * 64);        // fp8 table pong
    float* pooled8 = (float*)alloc((size_t)NPOOL * G * 64 * 4);
    short* wtg    = (short*)alloc(3 * 4096 * 2);          // W1T/W2T/W3T bf16
    int2*  staged = (int2*)alloc((size_t)NB * PADCAP * 8);

    const int bblk = (E + EPB - 1) / EPB;   // 391
    const int gblk = (N + 15) / 16;         // 6250: 16 nodes/block (4/wave)
    const int mblk = (N + 15) / 16;

    // -------- binned CSR build + normalization + W^T (2 kernels) --------
    hipMemsetAsync(binCursor, 0, 512 * 4, stream);
    k_binscatter<<<bblk, 512, 0, stream>>>(rowi, coli, ew, binCursor, staged,
                                           pooled8, W1, W2, W3, wtg,
                                           E, NB, NPOOL * G * 64);
    k_binfinal<<<NB, 1024, 0, stream>>>(staged, binCursor, csr, se, dinv, N);

    // -------- layer 1 gemm --------
    k_gemm<<<mblk, 256, 0, stream>>>(x, wtg, dinv, th4a, N);
    // -------- gather1 + BN1 + gemm2 (fused) --------
    k_fusedgg<<<gblk, 256, 0, stream>>>(csr, se, th4a, dinv, b1, g1, be1, m1, v1,
                                        wtg + 4096, th4b, N);
    // -------- gather2 + BN2 + gemm3 (fused) --------
    k_fusedgg<<<gblk, 256, 0, stream>>>(csr, se, th4b, dinv, b2, g2, be2, m2, v2,
                                        wtg + 8192, th4a, N);
    // -------- gather3 + BN3 + pool (block-merged atomics) --------
    k_gather<<<gblk, 256, 0, stream>>>(csr, se, th4a, dinv, b3, g3, be3, m3, v3,
                                       batch, pooled8, N, G * 64);
    // -------- FC head --------
    k_fc<<<G, 64, 0, stream>>>(pooled8, Wfc, bfc, (float*)d_out, G);
}